// Round 1
// baseline (2006.533 us; speedup 1.0000x reference)
//
#include <hip/hip_runtime.h>
#include <hip/hip_bf16.h>
#include <math.h>

#define N_NODES 20000
#define N_EDGES 320000
#define IN_FEAT 128
#define HIDDEN 256
#define OUT_DIM 12
#define NUM_SCALES 5
#define NUM_CONVS 3
#define NUM_GRAPHS 800
#define BN_EPS 1e-5f

// ---------------- CSR build ----------------
__global__ void hist_kernel(const int* __restrict__ dst, int* __restrict__ counts) {
    int e = blockIdx.x * blockDim.x + threadIdx.x;
    if (e < N_EDGES) atomicAdd(&counts[dst[e]], 1);
}

// single block, 1024 threads: inclusive scan of counts -> row_ptr[1..N], row_ptr[0]=0
// also writes norm[v] = rsqrt(max(deg,1))
__global__ void scan_kernel(const int* __restrict__ counts, int* __restrict__ row_ptr,
                            float* __restrict__ norm) {
    __shared__ int sdata[1024];
    const int tid = threadIdx.x;
    int running = 0;
    const int NCHUNK = (N_NODES + 1023) / 1024;
    for (int c = 0; c < NCHUNK; ++c) {
        int i = c * 1024 + tid;
        int v = (i < N_NODES) ? counts[i] : 0;
        if (i < N_NODES) norm[i] = rsqrtf(fmaxf((float)v, 1.0f));
        sdata[tid] = v;
        __syncthreads();
        for (int off = 1; off < 1024; off <<= 1) {
            int t = (tid >= off) ? sdata[tid - off] : 0;
            __syncthreads();
            sdata[tid] += t;
            __syncthreads();
        }
        if (i < N_NODES) row_ptr[i + 1] = running + sdata[tid];
        running += sdata[1023];
        __syncthreads();
    }
    if (tid == 0) row_ptr[0] = 0;
}

__global__ void scatter_kernel(const int* __restrict__ src, const int* __restrict__ dst,
                               const int* __restrict__ row_ptr, int* __restrict__ cursor,
                               int* __restrict__ edge_src) {
    int e = blockIdx.x * blockDim.x + threadIdx.x;
    if (e < N_EDGES) {
        int d = dst[e];
        int pos = atomicAdd(&cursor[d], 1);
        edge_src[row_ptr[d] + pos] = src[e];
    }
}

// graph_ids sorted -> contiguous node range per graph
__global__ void graph_start_kernel(const int* __restrict__ gid, int* __restrict__ gstart) {
    int i = blockIdx.x * blockDim.x + threadIdx.x;
    if (i >= N_NODES) return;
    int g = gid[i];
    if (i == 0) {
        for (int x = 0; x <= g; ++x) gstart[x] = 0;
    } else {
        int gp = gid[i - 1];
        for (int x = gp + 1; x <= g; ++x) gstart[x] = i;
    }
    if (i == N_NODES - 1) {
        for (int x = g + 1; x <= NUM_GRAPHS; ++x) gstart[x] = N_NODES;
    }
}

// ---------------- sparse aggregation: agg[v] = sum_{e: dst=v} norm[src_e] * h[src_e] ----------------
__global__ __launch_bounds__(HIDDEN) void gather_kernel(
    const float* __restrict__ h, const float* __restrict__ norm,
    const int* __restrict__ row_ptr, const int* __restrict__ edge_src,
    float* __restrict__ agg) {
    const int v = blockIdx.x;
    const int c = threadIdx.x;
    const int beg = row_ptr[v], end = row_ptr[v + 1];
    float acc = 0.f;
    for (int idx = beg; idx < end; ++idx) {
        int u = edge_src[idx];
        acc += norm[u] * h[(size_t)u * HIDDEN + c];
    }
    agg[(size_t)v * HIDDEN + c] = acc;
}

// ---------------- tiled f32 GEMM: C(MxN=256) = A(MxK) @ B(Kx256), optional row scale + BN+ReLU ----------------
template <bool SCALE_A, bool BNRELU>
__global__ __launch_bounds__(256) void gemm_kernel(
    const float* __restrict__ A, const float* __restrict__ B, float* __restrict__ C,
    int M, int K,
    const float* __restrict__ rowscale,
    const float* __restrict__ bn_gamma, const float* __restrict__ bn_beta,
    const float* __restrict__ bn_mean, const float* __restrict__ bn_var) {
    constexpr int BM = 64, BN = 64, BK = 16;
    __shared__ float As[BK][BM];
    __shared__ float Bs[BK][BN];
    const int tid = threadIdx.x;
    const int row0 = blockIdx.x * BM;
    const int col0 = blockIdx.y * BN;
    const int tx = tid & 15, ty = tid >> 4;
    const int am = tid >> 2, akq = (tid & 3) * 4;   // A tile load: row am, k quad akq
    const int bk = tid >> 4, bn_ = (tid & 15) * 4;  // B tile load: k row bk, col quad bn_
    const int arow = row0 + am;
    float ascale = 1.0f;
    if (SCALE_A && arow < M) ascale = rowscale[arow];
    float acc[4][4] = {};
    for (int k0 = 0; k0 < K; k0 += BK) {
        float4 av = make_float4(0.f, 0.f, 0.f, 0.f);
        if (arow < M) av = *reinterpret_cast<const float4*>(&A[(size_t)arow * K + k0 + akq]);
        if (SCALE_A) { av.x *= ascale; av.y *= ascale; av.z *= ascale; av.w *= ascale; }
        As[akq + 0][am] = av.x;
        As[akq + 1][am] = av.y;
        As[akq + 2][am] = av.z;
        As[akq + 3][am] = av.w;
        float4 bv = *reinterpret_cast<const float4*>(&B[(size_t)(k0 + bk) * HIDDEN + col0 + bn_]);
        *reinterpret_cast<float4*>(&Bs[bk][bn_]) = bv;
        __syncthreads();
#pragma unroll
        for (int k = 0; k < BK; ++k) {
            float4 a = *reinterpret_cast<const float4*>(&As[k][ty * 4]);
            float4 b = *reinterpret_cast<const float4*>(&Bs[k][tx * 4]);
            float ar[4] = {a.x, a.y, a.z, a.w};
            float br[4] = {b.x, b.y, b.z, b.w};
#pragma unroll
            for (int i = 0; i < 4; ++i)
#pragma unroll
                for (int j = 0; j < 4; ++j) acc[i][j] += ar[i] * br[j];
        }
        __syncthreads();
    }
#pragma unroll
    for (int i = 0; i < 4; ++i) {
        const int r = row0 + ty * 4 + i;
        if (r < M) {
            float4 o;
            float* op = &o.x;
#pragma unroll
            for (int j = 0; j < 4; ++j) {
                const int c = col0 + tx * 4 + j;
                float x = acc[i][j];
                if (BNRELU) {
                    float sc = bn_gamma[c] * rsqrtf(bn_var[c] + BN_EPS);
                    x = (x - bn_mean[c]) * sc + bn_beta[c];
                    x = fmaxf(x, 0.f);
                }
                op[j] = x;
            }
            *reinterpret_cast<float4*>(&C[(size_t)r * HIDDEN + col0 + tx * 4]) = o;
        }
    }
}

// ---------------- per-graph mean pool, accumulated across scales ----------------
__global__ __launch_bounds__(HIDDEN) void pool_kernel(const float* __restrict__ h,
                                                      const int* __restrict__ gstart,
                                                      float* __restrict__ pool) {
    const int g = blockIdx.x, c = threadIdx.x;
    const int beg = gstart[g], end = gstart[g + 1];
    float acc = 0.f;
    for (int v = beg; v < end; ++v) acc += h[(size_t)v * HIDDEN + c];
    float cnt = fmaxf((float)(end - beg), 1.0f);
    pool[g * HIDDEN + c] += acc / cnt;
}

// ---------------- final: mean over scales, L2 norm, fc1+leaky, out+sigmoid ----------------
__global__ __launch_bounds__(HIDDEN) void final_kernel(
    const float* __restrict__ pool,
    const float* __restrict__ W_fc1, const float* __restrict__ b_fc1,
    const float* __restrict__ W_out, const float* __restrict__ b_out,
    float* __restrict__ out) {
    __shared__ float hv[HIDDEN];
    __shared__ float h1[HIDDEN];
    __shared__ float red[HIDDEN];
    const int g = blockIdx.x, t = threadIdx.x;
    float x = pool[g * HIDDEN + t] * (1.0f / NUM_SCALES);
    red[t] = x * x;
    __syncthreads();
    for (int off = 128; off > 0; off >>= 1) {
        if (t < off) red[t] += red[t + off];
        __syncthreads();
    }
    float inv = 1.0f / fmaxf(sqrtf(red[0]), 1e-12f);
    hv[t] = x * inv;
    __syncthreads();
    float acc = b_fc1[t];
    for (int k = 0; k < HIDDEN; ++k) acc += hv[k] * W_fc1[k * HIDDEN + t];
    h1[t] = (acc > 0.f) ? acc : 0.01f * acc;
    __syncthreads();
    if (t < OUT_DIM) {
        float o = b_out[t];
        for (int k = 0; k < HIDDEN; ++k) o += h1[k] * W_out[k * OUT_DIM + t];
        out[g * OUT_DIM + t] = 1.0f / (1.0f + expf(-o));
    }
}

extern "C" void kernel_launch(void* const* d_in, const int* in_sizes, int n_in,
                              void* d_out, int out_size, void* d_ws, size_t ws_size,
                              hipStream_t stream) {
    const float* features  = (const float*)d_in[0];
    const int*   src       = (const int*)d_in[1];
    const int*   dst       = (const int*)d_in[2];
    const int*   graph_ids = (const int*)d_in[3];
    // d_in[4] = num_graphs scalar (hardcoded NUM_GRAPHS)
    const float* W_proj   = (const float*)d_in[5];
    const float* W_conv   = (const float*)d_in[6];
    const float* bn_gamma = (const float*)d_in[7];
    const float* bn_beta  = (const float*)d_in[8];
    const float* bn_mean  = (const float*)d_in[9];
    const float* bn_var   = (const float*)d_in[10];
    const float* W_fc1    = (const float*)d_in[11];
    const float* b_fc1    = (const float*)d_in[12];
    const float* W_out    = (const float*)d_in[13];
    const float* b_out    = (const float*)d_in[14];
    float* out = (float*)d_out;

    // workspace layout (4-byte units; h aligned to 16B)
    float* norm    = (float*)d_ws;                 // N
    int*   row_ptr = (int*)(norm + N_NODES);       // N+1
    int*   cursor  = row_ptr + N_NODES + 1;        // N
    int*   edge_src = cursor + N_NODES;            // E
    int*   gstart  = edge_src + N_EDGES;           // NUM_GRAPHS+1
    size_t ofs = (size_t)N_NODES + (N_NODES + 1) + N_NODES + N_EDGES + (NUM_GRAPHS + 1);
    ofs = (ofs + 3) & ~(size_t)3;  // 16B align
    float* h    = (float*)d_ws + ofs;              // N*HIDDEN
    float* agg  = h + (size_t)N_NODES * HIDDEN;    // N*HIDDEN
    float* pool = agg + (size_t)N_NODES * HIDDEN;  // NUM_GRAPHS*HIDDEN

    // CSR build
    hipMemsetAsync(cursor, 0, N_NODES * sizeof(int), stream);
    hist_kernel<<<(N_EDGES + 255) / 256, 256, 0, stream>>>(dst, cursor);
    scan_kernel<<<1, 1024, 0, stream>>>(cursor, row_ptr, norm);
    hipMemsetAsync(cursor, 0, N_NODES * sizeof(int), stream);
    scatter_kernel<<<(N_EDGES + 255) / 256, 256, 0, stream>>>(src, dst, row_ptr, cursor, edge_src);
    graph_start_kernel<<<(N_NODES + 255) / 256, 256, 0, stream>>>(graph_ids, gstart);
    hipMemsetAsync(pool, 0, NUM_GRAPHS * HIDDEN * sizeof(float), stream);

    const int MT = (N_NODES + 63) / 64;  // 313
    for (int s = 0; s < NUM_SCALES; ++s) {
        gemm_kernel<false, false><<<dim3(MT, 4), 256, 0, stream>>>(
            features, W_proj + (size_t)s * IN_FEAT * HIDDEN, h, N_NODES, IN_FEAT,
            nullptr, nullptr, nullptr, nullptr, nullptr);
        for (int i = 0; i < NUM_CONVS; ++i) {
            gather_kernel<<<N_NODES, HIDDEN, 0, stream>>>(h, norm, row_ptr, edge_src, agg);
            const size_t li = (size_t)(s * NUM_CONVS + i);
            gemm_kernel<true, true><<<dim3(MT, 4), 256, 0, stream>>>(
                agg, W_conv + li * HIDDEN * HIDDEN, h, N_NODES, HIDDEN,
                norm, bn_gamma + li * HIDDEN, bn_beta + li * HIDDEN,
                bn_mean + li * HIDDEN, bn_var + li * HIDDEN);
        }
        pool_kernel<<<NUM_GRAPHS, HIDDEN, 0, stream>>>(h, gstart, pool);
    }
    final_kernel<<<NUM_GRAPHS, HIDDEN, 0, stream>>>(pool, W_fc1, b_fc1, W_out, b_out, out);
}

// Round 2
// 595.722 us; speedup vs baseline: 3.3682x; 3.3682x over previous
//
#include <hip/hip_runtime.h>
#include <hip/hip_bf16.h>
#include <math.h>

#define N_NODES 20000
#define N_EDGES 320000
#define IN_FEAT 128
#define HIDDEN 256
#define OUT_DIM 12
#define NUM_SCALES 5
#define NUM_CONVS 3
#define NUM_GRAPHS 800
#define BN_EPS 1e-5f
#define M_PAD 20096  // 157 * 128

typedef __attribute__((ext_vector_type(8))) short bf16x8;
typedef __attribute__((ext_vector_type(4))) float f32x4;

__device__ __forceinline__ float bf2f(unsigned short u) {
    return __uint_as_float((unsigned)u << 16);
}
__device__ __forceinline__ unsigned short f2bf(float x) {
    unsigned u = __float_as_uint(x);
    return (unsigned short)((u + 0x7fffu + ((u >> 16) & 1u)) >> 16);
}
__device__ __forceinline__ void load_lds16(const void* g, void* l) {
    __builtin_amdgcn_global_load_lds(
        (const __attribute__((address_space(1))) unsigned int*)g,
        (__attribute__((address_space(3))) unsigned int*)l, 16, 0, 0);
}

// ---------------- CSR build ----------------
__global__ void hist_kernel(const int* __restrict__ dst, int* __restrict__ counts) {
    int e = blockIdx.x * blockDim.x + threadIdx.x;
    if (e < N_EDGES) atomicAdd(&counts[dst[e]], 1);
}

__global__ void scan_kernel(const int* __restrict__ counts, int* __restrict__ row_ptr,
                            float* __restrict__ norm) {
    __shared__ int sdata[1024];
    const int tid = threadIdx.x;
    int running = 0;
    const int NCHUNK = (N_NODES + 1023) / 1024;
    for (int c = 0; c < NCHUNK; ++c) {
        int i = c * 1024 + tid;
        int v = (i < N_NODES) ? counts[i] : 0;
        if (i < N_NODES) norm[i] = rsqrtf(fmaxf((float)v, 1.0f));
        sdata[tid] = v;
        __syncthreads();
        for (int off = 1; off < 1024; off <<= 1) {
            int t = (tid >= off) ? sdata[tid - off] : 0;
            __syncthreads();
            sdata[tid] += t;
            __syncthreads();
        }
        if (i < N_NODES) row_ptr[i + 1] = running + sdata[tid];
        running += sdata[1023];
        __syncthreads();
    }
    if (tid == 0) row_ptr[0] = 0;
}

__global__ void scatter_kernel(const int* __restrict__ src, const int* __restrict__ dst,
                               const int* __restrict__ row_ptr, int* __restrict__ cursor,
                               int* __restrict__ edge_src) {
    int e = blockIdx.x * blockDim.x + threadIdx.x;
    if (e < N_EDGES) {
        int d = dst[e];
        int pos = atomicAdd(&cursor[d], 1);
        edge_src[row_ptr[d] + pos] = src[e];
    }
}

__global__ void graph_start_kernel(const int* __restrict__ gid, int* __restrict__ gstart) {
    int i = blockIdx.x * blockDim.x + threadIdx.x;
    if (i >= N_NODES) return;
    int g = gid[i];
    if (i == 0) {
        for (int x = 0; x <= g; ++x) gstart[x] = 0;
    } else {
        int gp = gid[i - 1];
        for (int x = gp + 1; x <= g; ++x) gstart[x] = i;
    }
    if (i == N_NODES - 1) {
        for (int x = g + 1; x <= NUM_GRAPHS; ++x) gstart[x] = N_NODES;
    }
}

// ---------------- small prep kernels ----------------
__global__ void bn_precompute(const float* __restrict__ g, const float* __restrict__ b,
                              const float* __restrict__ m, const float* __restrict__ v,
                              float* __restrict__ scale, float* __restrict__ shift) {
    int i = blockIdx.x * 256 + threadIdx.x;  // 15*256
    float sc = g[i] * rsqrtf(v[i] + BN_EPS);
    scale[i] = sc;
    shift[i] = b[i] - m[i] * sc;
}

// features f32 [N_NODES][128] -> bf16 [M_PAD][128], pad rows zero
__global__ void feat_convert(const float* __restrict__ f, unsigned short* __restrict__ o) {
    int i = blockIdx.x * 256 + threadIdx.x;  // over M_PAD*128/4
    int e0 = i * 4;
    int r = e0 >> 7, c = e0 & 127;
    float4 v = make_float4(0.f, 0.f, 0.f, 0.f);
    if (r < N_NODES) v = *reinterpret_cast<const float4*>(&f[(size_t)r * IN_FEAT + c]);
    ushort4 u;
    u.x = f2bf(v.x); u.y = f2bf(v.y); u.z = f2bf(v.z); u.w = f2bf(v.w);
    *reinterpret_cast<ushort4*>(&o[e0]) = u;
}

// in: [b][K][N] f32 row-major -> out: [b][N][K] bf16 (i.e. B^T)
__global__ void transpose_bf16(const float* __restrict__ in, unsigned short* __restrict__ out,
                               int K, int N) {
    __shared__ float tile[32][33];
    const int b = blockIdx.z;
    in += (size_t)b * K * N;
    out += (size_t)b * K * N;
    const int k0 = blockIdx.x * 32, n0 = blockIdx.y * 32;
    for (int i = threadIdx.y; i < 32; i += 8)
        tile[i][threadIdx.x] = in[(size_t)(k0 + i) * N + n0 + threadIdx.x];
    __syncthreads();
    for (int i = threadIdx.y; i < 32; i += 8)
        out[(size_t)(n0 + i) * K + k0 + threadIdx.x] = f2bf(tile[threadIdx.x][i]);
}

// ---------------- gather: agg[v] = norm[v] * sum_e norm[src] * h[src] (bf16) ----------------
__global__ __launch_bounds__(256) void gather_bf16(
    const unsigned short* __restrict__ h, size_t h_zstride,
    const float* __restrict__ norm,
    const int* __restrict__ row_ptr, const int* __restrict__ edge_src,
    unsigned short* __restrict__ agg, size_t a_zstride) {
    const int wave = threadIdx.x >> 6, lane = threadIdx.x & 63;
    const int v = blockIdx.x * 4 + wave;
    if (v >= N_NODES) return;
    const unsigned short* hb = h + (size_t)blockIdx.y * h_zstride;
    const int beg = row_ptr[v], end = row_ptr[v + 1];
    const int c = lane * 4;
    float a0 = 0.f, a1 = 0.f, a2 = 0.f, a3 = 0.f;
    int i = beg;
    for (; i + 1 < end; i += 2) {
        const int u0 = edge_src[i], u1 = edge_src[i + 1];
        const float n0 = norm[u0], n1 = norm[u1];
        const ushort4 r0 = *reinterpret_cast<const ushort4*>(&hb[(size_t)u0 * HIDDEN + c]);
        const ushort4 r1 = *reinterpret_cast<const ushort4*>(&hb[(size_t)u1 * HIDDEN + c]);
        a0 += n0 * bf2f(r0.x) + n1 * bf2f(r1.x);
        a1 += n0 * bf2f(r0.y) + n1 * bf2f(r1.y);
        a2 += n0 * bf2f(r0.z) + n1 * bf2f(r1.z);
        a3 += n0 * bf2f(r0.w) + n1 * bf2f(r1.w);
    }
    if (i < end) {
        const int u0 = edge_src[i];
        const float n0 = norm[u0];
        const ushort4 r0 = *reinterpret_cast<const ushort4*>(&hb[(size_t)u0 * HIDDEN + c]);
        a0 += n0 * bf2f(r0.x);
        a1 += n0 * bf2f(r0.y);
        a2 += n0 * bf2f(r0.z);
        a3 += n0 * bf2f(r0.w);
    }
    const float nv = norm[v];
    ushort4 o;
    o.x = f2bf(nv * a0); o.y = f2bf(nv * a1); o.z = f2bf(nv * a2); o.w = f2bf(nv * a3);
    *reinterpret_cast<ushort4*>(&agg[(size_t)blockIdx.y * a_zstride + (size_t)v * HIDDEN + c]) = o;
}

// ---------------- MFMA GEMM: C[M_PAD x 256] = A[M_PAD x K] @ Bt^T, optional BN+ReLU ----------------
// A row-major bf16, Bt = B^T row-major bf16 [256][K], C bf16 [M_PAD][256]
template <int K, bool BNRELU>
__global__ __launch_bounds__(256, 2) void mfma_gemm(
    const unsigned short* __restrict__ A, size_t a_zstride,
    const unsigned short* __restrict__ Bt, size_t b_zstride,
    unsigned short* __restrict__ C, size_t c_zstride,
    const float* __restrict__ bn_scale, const float* __restrict__ bn_shift, int bn_zstride) {
    constexpr int BK = 64;
    __shared__ __align__(16) unsigned short As[128 * BK];
    __shared__ __align__(16) unsigned short Bs[128 * BK];
    const int z = blockIdx.z;
    A += (size_t)z * a_zstride;
    Bt += (size_t)z * b_zstride;
    C += (size_t)z * c_zstride;
    const int tid = threadIdx.x, lane = tid & 63, wave = tid >> 6;
    const int wr = wave >> 1, wc = wave & 1;
    const int r0 = blockIdx.x * 128, c0 = blockIdx.y * 128;

    // staging geometry: per issue 64 lanes x 16B = 8 rows of 128B (64 bf16)
    const int lrow = lane >> 3;              // row within 8-row group
    const int kch = (lane & 7) ^ lrow;       // logical k-chunk (XOR pre-swizzled source)
    // fragment read geometry
    const int frow = lane & 15;
    const int kgrp = lane >> 4;

    f32x4 acc[4][4];
#pragma unroll
    for (int i = 0; i < 4; ++i)
#pragma unroll
        for (int j = 0; j < 4; ++j) acc[i][j] = (f32x4)0.f;

    // LDS element offsets for fragment reads (swizzled): row*64 + (chunk^(row&7))*8
    int aoff[4][2], boff[4][2];
#pragma unroll
    for (int fm = 0; fm < 4; ++fm) {
        const int ra = wr * 64 + fm * 16 + frow;
        const int rb = wc * 64 + fm * 16 + frow;
#pragma unroll
        for (int ks = 0; ks < 2; ++ks) {
            aoff[fm][ks] = ra * 64 + ((ks * 4 + kgrp) ^ (ra & 7)) * 8;
            boff[fm][ks] = rb * 64 + ((ks * 4 + kgrp) ^ (rb & 7)) * 8;
        }
    }

    constexpr int NK = K / BK;
#pragma unroll
    for (int k0 = 0; k0 < NK; ++k0) {
        const int kk = k0 * BK;
#pragma unroll
        for (int i = 0; i < 4; ++i) {
            const int tb = wave * 32 + i * 8;
            load_lds16(&A[(size_t)(r0 + tb + lrow) * K + kk + kch * 8], &As[tb * 64]);
            load_lds16(&Bt[(size_t)(c0 + tb + lrow) * K + kk + kch * 8], &Bs[tb * 64]);
        }
        __syncthreads();
#pragma unroll
        for (int ks = 0; ks < 2; ++ks) {
            bf16x8 af[4], bfr[4];
#pragma unroll
            for (int fm = 0; fm < 4; ++fm) af[fm] = *reinterpret_cast<const bf16x8*>(&As[aoff[fm][ks]]);
#pragma unroll
            for (int fn = 0; fn < 4; ++fn) bfr[fn] = *reinterpret_cast<const bf16x8*>(&Bs[boff[fn][ks]]);
#pragma unroll
            for (int fm = 0; fm < 4; ++fm)
#pragma unroll
                for (int fn = 0; fn < 4; ++fn)
                    acc[fm][fn] = __builtin_amdgcn_mfma_f32_16x16x32_bf16(af[fm], bfr[fn], acc[fm][fn], 0, 0, 0);
        }
        __syncthreads();
    }

    // epilogue: D row = (lane>>4)*4 + reg, col = lane&15 within each 16x16 fragment
#pragma unroll
    for (int fn = 0; fn < 4; ++fn) {
        const int col = c0 + wc * 64 + fn * 16 + frow;
        float sc = 1.f, sh = 0.f;
        if (BNRELU) {
            sc = bn_scale[z * bn_zstride + col];
            sh = bn_shift[z * bn_zstride + col];
        }
#pragma unroll
        for (int fm = 0; fm < 4; ++fm) {
            const int rbase = r0 + wr * 64 + fm * 16 + kgrp * 4;
#pragma unroll
            for (int r = 0; r < 4; ++r) {
                float x = acc[fm][fn][r];
                if (BNRELU) x = fmaxf(x * sc + sh, 0.f);
                C[(size_t)(rbase + r) * HIDDEN + col] = f2bf(x);
            }
        }
    }
}

// ---------------- per-graph mean pool ----------------
__global__ __launch_bounds__(256) void pool_kernel(
    const unsigned short* __restrict__ h, size_t h_zstride,
    const int* __restrict__ gstart, float* __restrict__ pool, int s0) {
    const int g = blockIdx.x, c = threadIdx.x;
    const int s = s0 + blockIdx.y;
    const unsigned short* hb = h + (size_t)blockIdx.y * h_zstride;
    const int beg = gstart[g], end = gstart[g + 1];
    float acc = 0.f;
    for (int v = beg; v < end; ++v) acc += bf2f(hb[(size_t)v * HIDDEN + c]);
    pool[((size_t)s * NUM_GRAPHS + g) * HIDDEN + c] = acc / fmaxf((float)(end - beg), 1.f);
}

// ---------------- final MLP ----------------
__global__ __launch_bounds__(256) void final_kernel(
    const float* __restrict__ pool,
    const float* __restrict__ W_fc1, const float* __restrict__ b_fc1,
    const float* __restrict__ W_out, const float* __restrict__ b_out,
    float* __restrict__ out) {
    __shared__ float hv[HIDDEN];
    __shared__ float h1[HIDDEN];
    __shared__ float red[HIDDEN];
    const int g = blockIdx.x, t = threadIdx.x;
    float x = 0.f;
#pragma unroll
    for (int s = 0; s < NUM_SCALES; ++s) x += pool[((size_t)s * NUM_GRAPHS + g) * HIDDEN + t];
    x *= (1.0f / NUM_SCALES);
    red[t] = x * x;
    __syncthreads();
    for (int off = 128; off > 0; off >>= 1) {
        if (t < off) red[t] += red[t + off];
        __syncthreads();
    }
    float inv = 1.0f / fmaxf(sqrtf(red[0]), 1e-12f);
    hv[t] = x * inv;
    __syncthreads();
    float acc = b_fc1[t];
    for (int k = 0; k < HIDDEN; ++k) acc += hv[k] * W_fc1[k * HIDDEN + t];
    h1[t] = (acc > 0.f) ? acc : 0.01f * acc;
    __syncthreads();
    if (t < OUT_DIM) {
        float o = b_out[t];
        for (int k = 0; k < HIDDEN; ++k) o += h1[k] * W_out[k * OUT_DIM + t];
        out[g * OUT_DIM + t] = 1.0f / (1.0f + expf(-o));
    }
}

extern "C" void kernel_launch(void* const* d_in, const int* in_sizes, int n_in,
                              void* d_out, int out_size, void* d_ws, size_t ws_size,
                              hipStream_t stream) {
    const float* features  = (const float*)d_in[0];
    const int*   src       = (const int*)d_in[1];
    const int*   dst       = (const int*)d_in[2];
    const int*   graph_ids = (const int*)d_in[3];
    const float* W_proj   = (const float*)d_in[5];
    const float* W_conv   = (const float*)d_in[6];
    const float* bn_gamma = (const float*)d_in[7];
    const float* bn_beta  = (const float*)d_in[8];
    const float* bn_mean  = (const float*)d_in[9];
    const float* bn_var   = (const float*)d_in[10];
    const float* W_fc1    = (const float*)d_in[11];
    const float* b_fc1    = (const float*)d_in[12];
    const float* W_out    = (const float*)d_in[13];
    const float* b_out    = (const float*)d_in[14];
    float* out = (float*)d_out;

    // workspace carve-out (256B aligned)
    size_t off = 0;
    char* base = (char*)d_ws;
    auto alloc = [&](size_t bytes) -> void* {
        void* p = base + off;
        off += (bytes + 255) & ~(size_t)255;
        return p;
    };
    float* norm      = (float*)alloc(N_NODES * 4);
    int*   row_ptr   = (int*)alloc((N_NODES + 1) * 4);
    int*   cursor    = (int*)alloc(N_NODES * 4);
    int*   edge_src  = (int*)alloc(N_EDGES * 4);
    int*   gstart    = (int*)alloc((NUM_GRAPHS + 1) * 4);
    float* bn_scale  = (float*)alloc(NUM_SCALES * NUM_CONVS * HIDDEN * 4);
    float* bn_shift  = (float*)alloc(NUM_SCALES * NUM_CONVS * HIDDEN * 4);
    unsigned short* feat_b  = (unsigned short*)alloc((size_t)M_PAD * IN_FEAT * 2);
    unsigned short* Wt_proj = (unsigned short*)alloc((size_t)NUM_SCALES * HIDDEN * IN_FEAT * 2);
    unsigned short* Wt_conv = (unsigned short*)alloc((size_t)NUM_SCALES * NUM_CONVS * HIDDEN * HIDDEN * 2);
    float* pool      = (float*)alloc((size_t)NUM_SCALES * NUM_GRAPHS * HIDDEN * 4);

    const size_t HSZ = (size_t)M_PAD * HIDDEN;  // elements per scale
    const bool batched = (ws_size - off) >= (2 * NUM_SCALES * HSZ * 2 + 1024);
    const int nsb = batched ? NUM_SCALES : 1;
    unsigned short* h_all   = (unsigned short*)alloc((size_t)nsb * HSZ * 2);
    unsigned short* agg_all = (unsigned short*)alloc((size_t)nsb * HSZ * 2);

    // ---- setup ----
    hipMemsetAsync(cursor, 0, N_NODES * sizeof(int), stream);
    hist_kernel<<<(N_EDGES + 255) / 256, 256, 0, stream>>>(dst, cursor);
    scan_kernel<<<1, 1024, 0, stream>>>(cursor, row_ptr, norm);
    hipMemsetAsync(cursor, 0, N_NODES * sizeof(int), stream);
    scatter_kernel<<<(N_EDGES + 255) / 256, 256, 0, stream>>>(src, dst, row_ptr, cursor, edge_src);
    graph_start_kernel<<<(N_NODES + 255) / 256, 256, 0, stream>>>(graph_ids, gstart);
    bn_precompute<<<NUM_SCALES * NUM_CONVS, 256, 0, stream>>>(bn_gamma, bn_beta, bn_mean, bn_var,
                                                              bn_scale, bn_shift);
    feat_convert<<<(M_PAD * IN_FEAT / 4 + 255) / 256, 256, 0, stream>>>(features, feat_b);
    transpose_bf16<<<dim3(IN_FEAT / 32, HIDDEN / 32, NUM_SCALES), dim3(32, 8), 0, stream>>>(
        W_proj, Wt_proj, IN_FEAT, HIDDEN);
    transpose_bf16<<<dim3(HIDDEN / 32, HIDDEN / 32, NUM_SCALES * NUM_CONVS), dim3(32, 8), 0, stream>>>(
        W_conv, Wt_conv, HIDDEN, HIDDEN);

    const int MT = M_PAD / 128;  // 157
    if (batched) {
        mfma_gemm<IN_FEAT, false><<<dim3(MT, 2, NUM_SCALES), 256, 0, stream>>>(
            feat_b, 0, Wt_proj, (size_t)HIDDEN * IN_FEAT, h_all, HSZ, nullptr, nullptr, 0);
        for (int i = 0; i < NUM_CONVS; ++i) {
            gather_bf16<<<dim3(N_NODES / 4, NUM_SCALES), 256, 0, stream>>>(
                h_all, HSZ, norm, row_ptr, edge_src, agg_all, HSZ);
            mfma_gemm<HIDDEN, true><<<dim3(MT, 2, NUM_SCALES), 256, 0, stream>>>(
                agg_all, HSZ, Wt_conv + (size_t)i * HIDDEN * HIDDEN, (size_t)NUM_CONVS * HIDDEN * HIDDEN,
                h_all, HSZ, bn_scale + i * HIDDEN, bn_shift + i * HIDDEN, NUM_CONVS * HIDDEN);
        }
        pool_kernel<<<dim3(NUM_GRAPHS, NUM_SCALES), 256, 0, stream>>>(h_all, HSZ, gstart, pool, 0);
    } else {
        for (int s = 0; s < NUM_SCALES; ++s) {
            mfma_gemm<IN_FEAT, false><<<dim3(MT, 2, 1), 256, 0, stream>>>(
                feat_b, 0, Wt_proj + (size_t)s * HIDDEN * IN_FEAT, 0, h_all, 0, nullptr, nullptr, 0);
            for (int i = 0; i < NUM_CONVS; ++i) {
                const size_t li = (size_t)(s * NUM_CONVS + i);
                gather_bf16<<<dim3(N_NODES / 4, 1), 256, 0, stream>>>(
                    h_all, 0, norm, row_ptr, edge_src, agg_all, 0);
                mfma_gemm<HIDDEN, true><<<dim3(MT, 2, 1), 256, 0, stream>>>(
                    agg_all, 0, Wt_conv + li * HIDDEN * HIDDEN, 0, h_all, 0,
                    bn_scale + li * HIDDEN, bn_shift + li * HIDDEN, 0);
            }
            pool_kernel<<<dim3(NUM_GRAPHS, 1), 256, 0, stream>>>(h_all, 0, gstart, pool, s);
        }
    }
    final_kernel<<<NUM_GRAPHS, 256, 0, stream>>>(pool, W_fc1, b_fc1, W_out, b_out, out);
}